// Round 5
// baseline (360.683 us; speedup 1.0000x reference)
//
#include <hip/hip_runtime.h>
#include <hip/hip_bf16.h>

#define SEQ 2048
#define HID 3584
#define NQH 28
#define NKVH 4
#define HD 128
#define QKVN 4608
#define WIN 1024

typedef __bf16 bf16x8 __attribute__((ext_vector_type(8)));
typedef float f32x4 __attribute__((ext_vector_type(4)));
typedef unsigned int u32x4 __attribute__((ext_vector_type(4)));
typedef unsigned short u16x4 __attribute__((ext_vector_type(4)));

static __device__ __forceinline__ unsigned short f2bf(float f) {
  unsigned int u = __builtin_bit_cast(unsigned int, f);
  u += 0x7fffu + ((u >> 16) & 1u);
  return (unsigned short)(u >> 16);
}
static __device__ __forceinline__ float bf2f(unsigned short h) {
  unsigned int u = ((unsigned int)h) << 16;
  return __builtin_bit_cast(float, u);
}

// async global->LDS, 16B per lane. lds base must be wave-uniform; HW adds lane*16.
static __device__ __forceinline__ void gload16(const unsigned short* g, unsigned short* l) {
  __builtin_amdgcn_global_load_lds(
      (const __attribute__((address_space(1))) unsigned int*)g,
      (__attribute__((address_space(3))) unsigned int*)l, 16, 0, 0);
}

// ---------- cast f32 -> bf16, 8 elems/thread ----------
__global__ __launch_bounds__(256) void k_cast8(const float* __restrict__ in,
                                               unsigned short* __restrict__ out, int n8) {
  int i = blockIdx.x * 256 + threadIdx.x;
  if (i >= n8) return;
  f32x4 a = ((const f32x4*)in)[2 * i];
  f32x4 b = ((const f32x4*)in)[2 * i + 1];
  union { unsigned short s[8]; u32x4 v; } u;
#pragma unroll
  for (int j = 0; j < 4; j++) { u.s[j] = f2bf(a[j]); u.s[4 + j] = f2bf(b[j]); }
  ((u32x4*)out)[i] = u.v;
}

// ---------- transpose + cast: out[c][r] = bf16(in[r][c]), R,C multiples of 64 ----------
__global__ __launch_bounds__(256) void k_tcast(const float* __restrict__ in,
                                               unsigned short* __restrict__ out, int R, int C) {
  __shared__ unsigned short tile[64][66];
  const int r0 = blockIdx.x * 64, c0 = blockIdx.y * 64;
  const int t = threadIdx.x;
  const int rg = t >> 4, cg = t & 15;
#pragma unroll
  for (int i = 0; i < 4; i++) {
    int rl = rg + i * 16;
    f32x4 v = *(const f32x4*)(in + (size_t)(r0 + rl) * C + c0 + cg * 4);
#pragma unroll
    for (int j = 0; j < 4; j++) tile[rl][cg * 4 + j] = f2bf(v[j]);
  }
  __syncthreads();
#pragma unroll
  for (int i = 0; i < 4; i++) {
    int cl = rg + i * 16;
    u16x4 o;
#pragma unroll
    for (int j = 0; j < 4; j++) o[j] = tile[cg * 4 + j][cl];
    *(u16x4*)(out + (size_t)(c0 + cl) * R + r0 + cg * 4) = o;
  }
}

// ---------- V transpose (bf16): vt[g*128+d][s] = qkv[s][4096 + g*128 + d] ----------
__global__ __launch_bounds__(256) void k_vtrans(const unsigned short* __restrict__ qkv,
                                                unsigned short* __restrict__ vt) {
  __shared__ unsigned short tile[64][66];
  const int r0 = blockIdx.x * 64;  // seq
  const int c0 = blockIdx.y * 64;  // g*128+d in [0,512)
  const int t = threadIdx.x;
  const int rg = t >> 4, cg = t & 15;
#pragma unroll
  for (int i = 0; i < 4; i++) {
    int rl = rg + i * 16;
    u16x4 v = *(const u16x4*)(qkv + (size_t)(r0 + rl) * QKVN + (NQH + NKVH) * HD + c0 + cg * 4);
#pragma unroll
    for (int j = 0; j < 4; j++) tile[rl][cg * 4 + j] = v[j];
  }
  __syncthreads();
#pragma unroll
  for (int i = 0; i < 4; i++) {
    int cl = rg + i * 16;
    u16x4 o;
#pragma unroll
    for (int j = 0; j < 4; j++) o[j] = tile[cg * 4 + j][cl];
    *(u16x4*)(vt + (size_t)(c0 + cl) * SEQ + r0 + cg * 4) = o;
  }
}

// ---------- RoPE in-place on q (heads 0..27) and k (heads 28..31) ----------
__global__ __launch_bounds__(256) void k_rope(unsigned short* __restrict__ qkv,
                                              const float* __restrict__ cosb,
                                              const float* __restrict__ sinb) {
  int idx = blockIdx.x * 256 + threadIdx.x;  // 2048*32*16 total
  int d4 = idx & 15;
  int head = (idx >> 4) & 31;
  int s = idx >> 9;
  unsigned short* row = qkv + (size_t)s * QKVN + head * HD;  // heads 0..31 are contiguous
  int d = d4 * 4;
  u16x4 x1v = *(u16x4*)(row + d);
  u16x4 x2v = *(u16x4*)(row + 64 + d);
  f32x4 c1 = *(const f32x4*)(cosb + s * HD + d);
  f32x4 s1 = *(const f32x4*)(sinb + s * HD + d);
  f32x4 c2 = *(const f32x4*)(cosb + s * HD + 64 + d);
  f32x4 s2 = *(const f32x4*)(sinb + s * HD + 64 + d);
  u16x4 o1, o2;
#pragma unroll
  for (int j = 0; j < 4; j++) {
    float x1 = bf2f(x1v[j]), x2 = bf2f(x2v[j]);
    o1[j] = f2bf(x1 * c1[j] - x2 * s1[j]);
    o2[j] = f2bf(x2 * c2[j] + x1 * s2[j]);
  }
  *(u16x4*)(row + d) = o1;
  *(u16x4*)(row + 64 + d) = o2;
}

// ================= 256x256 software-pipelined GEMM =================
// C[M][N] = A[M][K] * Bt[N][K]^T. 8 waves (2M x 4N), per-wave 128x64.
// BK=64, LDS 128KB dbuf, XOR-swizzle (linear gload dest, inv-swz source).
// 4 phases/K-tile; operand ds_reads shifted ONE PHASE EARLY so they overlap
// the MFMA window (compiler inserts counted lgkm waits from reg deps):
//   ph1: rd B1[t](4)   | gload B(t+1) | MFMA q00(A0,B0)
//   ph2: rd A1[t](8)   |              | MFMA q01(A0,B1) | vmcnt(4): A(t+1) landed
//   ph3: rd A0[t+1](8) |              | MFMA q10(A1,B0) | vmcnt(0): B(t+1) landed
//   ph4: rd B0[t+1](4) | gload A(t+2) | MFMA q11(A1,B1)
// gloads waited 2+ phases after issue; never a fresh drain. Reads 24/wave/tile.

static __device__ __forceinline__ void g_stageA(const unsigned short* __restrict__ P,
                                                unsigned short* L, int r0, int K, int kt,
                                                int w, int l) {
#pragma unroll
  for (int i = 0; i < 4; i++) {
    int sbase = i * 512 + w * 64;
    int s = sbase + l;
    int row = s >> 3, sl = s & 7;
    int slsrc = sl ^ (row & 7);
    gload16(P + (size_t)(r0 + row) * K + kt * 64 + slsrc * 8, L + sbase * 8);
  }
}

#define RD_A(dst, buf, MQ)                                                                   \
  _Pragma("unroll") for (int mi = 0; mi < 4; mi++) {                                         \
    int row = wm * 128 + (MQ) * 64 + mi * 16 + li;                                           \
    _Pragma("unroll") for (int ks = 0; ks < 2; ks++)                                         \
        dst[mi][ks] = __builtin_bit_cast(                                                    \
            bf16x8, *(const u32x4*)((buf) + row * 64 + ((ks * 32 + lg * 8) ^ ((row & 7) << 3)))); \
  }
#define RD_B(dst, buf, NQ)                                                                   \
  _Pragma("unroll") for (int ni = 0; ni < 2; ni++) {                                         \
    int row = wn * 64 + (NQ) * 32 + ni * 16 + li;                                            \
    _Pragma("unroll") for (int ks = 0; ks < 2; ks++)                                         \
        dst[ni][ks] = __builtin_bit_cast(                                                    \
            bf16x8, *(const u32x4*)((buf) + row * 64 + ((ks * 32 + lg * 8) ^ ((row & 7) << 3)))); \
  }
#define MFMA16(MQ, NQ, AF, BF)                                                               \
  __builtin_amdgcn_s_setprio(1);                                                             \
  _Pragma("unroll") for (int mi = 0; mi < 4; mi++)                                           \
      _Pragma("unroll") for (int ni = 0; ni < 2; ni++)                                       \
          _Pragma("unroll") for (int ks = 0; ks < 2; ks++)                                   \
              acc[(MQ) * 4 + mi][(NQ) * 2 + ni] = __builtin_amdgcn_mfma_f32_16x16x32_bf16(   \
                  AF[mi][ks], BF[ni][ks], acc[(MQ) * 4 + mi][(NQ) * 2 + ni], 0, 0, 0);       \
  __builtin_amdgcn_s_setprio(0);
#define BAR_PIN()                  \
  __builtin_amdgcn_s_barrier();    \
  __builtin_amdgcn_sched_barrier(0);

__global__ __launch_bounds__(512, 2) void k_gemm256(const unsigned short* __restrict__ A,
                                                    const unsigned short* __restrict__ Bt,
                                                    const float* __restrict__ bias,
                                                    void* __restrict__ Cout,
                                                    int M, int N, int K, int mode) {
  __shared__ unsigned short Al[2][256 * 64];
  __shared__ unsigned short Bl[2][256 * 64];

  const int gx = gridDim.x;  // M blocks
  const int nwg = gx * gridDim.y;
  const int lin = blockIdx.y * gx + blockIdx.x;
  const int chunk = nwg >> 3;  // grids are multiples of 8
  const int wg = (lin & 7) * chunk + (lin >> 3);
  const int m0 = (wg % gx) * 256, n0 = (wg / gx) * 256;

  const int t = threadIdx.x;
  const int w = t >> 6, l = t & 63, lg = l >> 4, li = l & 15;
  const int wm = w >> 2, wn = w & 3;  // 2 x 4 waves

  f32x4 acc[8][4] = {};
  const int nk = K >> 6;

  bf16x8 af0[4][2], af1[4][2], bf0[2][2], bf1[2][2];

  // prologue: stage tile 0; read tile-0 q00 operands; issue A(1)
  g_stageA(A, Al[0], m0, K, 0, w, l);
  g_stageA(Bt, Bl[0], n0, K, 0, w, l);
  asm volatile("s_waitcnt vmcnt(0)" ::: "memory");
  BAR_PIN()
  RD_A(af0, Al[0], 0)
  RD_B(bf0, Bl[0], 0)
  if (nk > 1) g_stageA(A, Al[1], m0, K, 1, w, l);
  BAR_PIN()

  for (int kt = 0; kt < nk; kt++) {
    const int cur = kt & 1;
    const unsigned short* Acur = Al[cur];
    const unsigned short* Bcur = Bl[cur];
    const unsigned short* Anxt = Al[cur ^ 1];
    const unsigned short* Bnxt = Bl[cur ^ 1];

    // ---- ph1 ----
    RD_B(bf1, Bcur, 1)
    if (kt + 1 < nk) g_stageA(Bt, Bl[cur ^ 1], n0, K, kt + 1, w, l);
    BAR_PIN()
    MFMA16(0, 0, af0, bf0)
    BAR_PIN()

    // ---- ph2 ----
    RD_A(af1, Acur, 1)
    BAR_PIN()
    MFMA16(0, 1, af0, bf1)
    if (kt + 1 < nk) {
      asm volatile("s_waitcnt vmcnt(4)" ::: "memory");  // A(t+1) landed; B(t+1) in flight
    } else {
      asm volatile("s_waitcnt vmcnt(0)" ::: "memory");
    }
    BAR_PIN()

    // ---- ph3 ---- (reads of tile t+1 are garbage on last iter; unused)
    RD_A(af0, Anxt, 0)
    BAR_PIN()
    MFMA16(1, 0, af1, bf0)
    asm volatile("s_waitcnt vmcnt(0)" ::: "memory");    // B(t+1) landed
    BAR_PIN()

    // ---- ph4 ----
    RD_B(bf0, Bnxt, 0)
    if (kt + 2 < nk) g_stageA(A, Al[cur], m0, K, kt + 2, w, l);
    BAR_PIN()
    MFMA16(1, 1, af1, bf1)
    BAR_PIN()
  }

  if (mode == 0) {
    float bv[4];
#pragma unroll
    for (int nf = 0; nf < 4; nf++) bv[nf] = bias[n0 + wn * 64 + nf * 16 + li];
    unsigned short* C16 = (unsigned short*)Cout;
#pragma unroll
    for (int mf = 0; mf < 8; mf++)
#pragma unroll
      for (int nf = 0; nf < 4; nf++)
#pragma unroll
        for (int r = 0; r < 4; r++) {
          int m = m0 + wm * 128 + mf * 16 + lg * 4 + r;
          int n = n0 + wn * 64 + nf * 16 + li;
          C16[(size_t)m * N + n] = f2bf(acc[mf][nf][r] + bv[nf]);
        }
  } else {
    float* Cf = (float*)Cout;
#pragma unroll
    for (int mf = 0; mf < 8; mf++)
#pragma unroll
      for (int nf = 0; nf < 4; nf++)
#pragma unroll
        for (int r = 0; r < 4; r++) {
          int m = m0 + wm * 128 + mf * 16 + lg * 4 + r;
          int n = n0 + wn * 64 + nf * 16 + li;
          Cf[(size_t)m * N + n] = acc[mf][nf][r];
        }
  }
}

// ---------- flash attention, sliding window, GQA ----------
// block = (qb, h): 64 q rows, head h (kv group h/7). 4 waves x 16 rows.
__global__ __launch_bounds__(256) void k_attn(const unsigned short* __restrict__ qkv,
                                              const unsigned short* __restrict__ vt,
                                              unsigned short* __restrict__ attnout) {
  __shared__ unsigned short Kl[64 * 128];
  __shared__ unsigned short Vl[128 * 64];
  __shared__ unsigned short Pl[4][16 * 64];

  const int qb = blockIdx.x;
  const int h = blockIdx.y;
  const int g = h / 7;
  const int t = threadIdx.x;
  const int w = t >> 6, l = t & 63, lg = l >> 4, li = l & 15;

  bf16x8 qf[4];
  {
    const int qrow = qb * 64 + w * 16 + li;
    const unsigned short* qp = qkv + (size_t)qrow * QKVN + h * HD;
#pragma unroll
    for (int ks = 0; ks < 4; ks++)
      qf[ks] = __builtin_bit_cast(bf16x8, *(const u32x4*)(qp + ks * 32 + lg * 8));
  }

  f32x4 oacc[8] = {};
  float mr[4], lr[4];
#pragma unroll
  for (int r = 0; r < 4; r++) { mr[r] = -1e30f; lr[r] = 0.f; }

  const int kt_lo = qb >= 16 ? qb - 16 : 0;
  const float scale = 0.088388347648318447f;  // 1/sqrt(128)

  for (int kt = kt_lo; kt <= qb; kt++) {
    __syncthreads();
    // stage K tile [64 keys][128 d], swizzled
#pragma unroll
    for (int i = 0; i < 4; i++) {
      int s = t + i * 256;
      int row = s >> 4, sl = s & 15;
      u32x4 v = *(const u32x4*)(qkv + (size_t)(kt * 64 + row) * QKVN + NQH * HD + g * HD + sl * 8);
      *(u32x4*)(Kl + row * 128 + ((sl ^ (row & 7)) * 8)) = v;
    }
    // stage V^T tile [128 d][64 keys], swizzled
#pragma unroll
    for (int i = 0; i < 4; i++) {
      int s = t + i * 256;
      int row = s >> 3, sl = s & 7;  // row = d
      u32x4 v = *(const u32x4*)(vt + (size_t)(g * HD + row) * SEQ + kt * 64 + sl * 8);
      *(u32x4*)(Vl + row * 64 + ((sl ^ (row & 7)) * 8)) = v;
    }
    __syncthreads();

    // S = Q K^T
    f32x4 sc[4] = {};
#pragma unroll
    for (int ks = 0; ks < 4; ks++) {
#pragma unroll
      for (int kb = 0; kb < 4; kb++) {
        int key = kb * 16 + li;
        int pos = (ks * 32 + lg * 8) ^ ((key & 7) << 3);
        bf16x8 kf = __builtin_bit_cast(bf16x8, *(const u32x4*)(Kl + key * 128 + pos));
        sc[kb] = __builtin_amdgcn_mfma_f32_16x16x32_bf16(qf[ks], kf, sc[kb], 0, 0, 0);
      }
    }

    // online softmax (rows partition by 16-lane group; reg r = row lg*4+r)
    float alpha[4];
#pragma unroll
    for (int r = 0; r < 4; r++) {
      int qg = qb * 64 + w * 16 + lg * 4 + r;
      float sv[4];
      float mx = -1e30f;
#pragma unroll
      for (int kb = 0; kb < 4; kb++) {
        int kg = kt * 64 + kb * 16 + li;
        float x = sc[kb][r] * scale;
        bool ok = (kg <= qg) && (qg - kg < WIN);
        sv[kb] = ok ? x : -1e30f;
        mx = fmaxf(mx, sv[kb]);
      }
#pragma unroll
      for (int off = 1; off < 16; off <<= 1) mx = fmaxf(mx, __shfl_xor(mx, off));
      float mn = fmaxf(mr[r], mx);
      alpha[r] = __expf(mr[r] - mn);
      float rs = 0.f;
      int q_l = lg * 4 + r;
#pragma unroll
      for (int kb = 0; kb < 4; kb++) {
        float p = (sv[kb] > -1e29f) ? __expf(sv[kb] - mn) : 0.f;
        rs += p;
        Pl[w][q_l * 64 + (((kb * 16 + li) ^ ((q_l & 7) << 3)))] = f2bf(p);
      }
#pragma unroll
      for (int off = 1; off < 16; off <<= 1) rs += __shfl_xor(rs, off);
      lr[r] = lr[r] * alpha[r] + rs;
      mr[r] = mn;
    }
#pragma unroll
    for (int db = 0; db < 8; db++)
#pragma unroll
      for (int r = 0; r < 4; r++) oacc[db][r] *= alpha[r];
    __syncthreads();  // P visible for A-fragment reads

    // O += P V
#pragma unroll
    for (int ks = 0; ks < 2; ks++) {
      int ppos = (ks * 32 + lg * 8) ^ ((li & 7) << 3);
      bf16x8 pf = __builtin_bit_cast(bf16x8, *(const u32x4*)(&Pl[w][li * 64 + ppos]));
#pragma unroll
      for (int db = 0; db < 8; db++) {
        int d = db * 16 + li;
        int vpos = (ks * 32 + lg * 8) ^ ((d & 7) << 3);
        bf16x8 vf = __builtin_bit_cast(bf16x8, *(const u32x4*)(Vl + d * 64 + vpos));
        oacc[db] = __builtin_amdgcn_mfma_f32_16x16x32_bf16(pf, vf, oacc[db], 0, 0, 0);
      }
    }
  }

#pragma unroll
  for (int r = 0; r < 4; r++) {
    float inv = 1.0f / lr[r];
    int qrow = qb * 64 + w * 16 + lg * 4 + r;
#pragma unroll
    for (int db = 0; db < 8; db++)
      attnout[(size_t)qrow * HID + h * HD + db * 16 + li] = f2bf(oacc[db][r] * inv);
  }
}

extern "C" void kernel_launch(void* const* d_in, const int* in_sizes, int n_in,
                              void* d_out, int out_size, void* d_ws, size_t ws_size,
                              hipStream_t stream) {
  const float* hidden = (const float*)d_in[0];
  const float* cosb = (const float*)d_in[1];
  const float* sinb = (const float*)d_in[2];
  const float* wqkv = (const float*)d_in[3];
  const float* bqkv = (const float*)d_in[4];
  const float* wo = (const float*)d_in[5];

  char* ws = (char*)d_ws;
  const size_t SZ_HBF = (size_t)SEQ * HID * 2;          // 14,680,064
  const size_t SZ_WQKVT = (size_t)QKVN * HID * 2;       // 33,030,144
  const size_t SZ_QKV = (size_t)SEQ * QKVN * 2;         // 18,874,368
  const size_t SZ_VT = (size_t)NKVH * HD * SEQ * 2;     // 2,097,152
  unsigned short* hbf = (unsigned short*)ws;
  unsigned short* wqkvT = (unsigned short*)(ws + SZ_HBF);
  unsigned short* qkv = (unsigned short*)(ws + SZ_HBF + SZ_WQKVT);
  unsigned short* vt = (unsigned short*)(ws + SZ_HBF + SZ_WQKVT + SZ_QKV);
  unsigned short* attn = (unsigned short*)(ws + SZ_HBF + SZ_WQKVT + SZ_QKV + SZ_VT);
  unsigned short* woT = wqkvT;  // reuse after QKV GEMM consumed wqkvT

  k_cast8<<<dim3(SEQ * HID / 8 / 256), 256, 0, stream>>>(hidden, hbf, SEQ * HID / 8);
  k_tcast<<<dim3(HID / 64, QKVN / 64), 256, 0, stream>>>(wqkv, wqkvT, HID, QKVN);
  k_gemm256<<<dim3(SEQ / 256, QKVN / 256), 512, 0, stream>>>(hbf, wqkvT, bqkv, qkv, SEQ, QKVN, HID, 0);
  k_rope<<<dim3(SEQ * 32 * 16 / 256), 256, 0, stream>>>(qkv, cosb, sinb);
  k_vtrans<<<dim3(SEQ / 64, (NKVH * HD) / 64), 256, 0, stream>>>(qkv, vt);
  k_tcast<<<dim3(HID / 64, HID / 64), 256, 0, stream>>>(wo, woT, HID, HID);
  k_attn<<<dim3(SEQ / 64, NQH), 256, 0, stream>>>(qkv, vt, attn);
  k_gemm256<<<dim3(SEQ / 256, HID / 256), 512, 0, stream>>>(attn, woT, nullptr, d_out, SEQ, HID, HID, 1);
}

// Round 6
// 317.446 us; speedup vs baseline: 1.1362x; 1.1362x over previous
//
#include <hip/hip_runtime.h>
#include <hip/hip_bf16.h>

#define SEQ 2048
#define HID 3584
#define NQH 28
#define NKVH 4
#define HD 128
#define QKVN 4608
#define WIN 1024

typedef __bf16 bf16x8 __attribute__((ext_vector_type(8)));
typedef float f32x4 __attribute__((ext_vector_type(4)));
typedef unsigned int u32x4 __attribute__((ext_vector_type(4)));
typedef unsigned short u16x4 __attribute__((ext_vector_type(4)));

static __device__ __forceinline__ unsigned short f2bf(float f) {
  unsigned int u = __builtin_bit_cast(unsigned int, f);
  u += 0x7fffu + ((u >> 16) & 1u);
  return (unsigned short)(u >> 16);
}
static __device__ __forceinline__ float bf2f(unsigned short h) {
  unsigned int u = ((unsigned int)h) << 16;
  return __builtin_bit_cast(float, u);
}

// async global->LDS, 16B per lane. lds base must be wave-uniform; HW adds lane*16.
static __device__ __forceinline__ void gload16(const unsigned short* g, unsigned short* l) {
  __builtin_amdgcn_global_load_lds(
      (const __attribute__((address_space(1))) unsigned int*)g,
      (__attribute__((address_space(3))) unsigned int*)l, 16, 0, 0);
}

// ---------- cast f32 -> bf16, 8 elems/thread ----------
__global__ __launch_bounds__(256) void k_cast8(const float* __restrict__ in,
                                               unsigned short* __restrict__ out, int n8) {
  int i = blockIdx.x * 256 + threadIdx.x;
  if (i >= n8) return;
  f32x4 a = ((const f32x4*)in)[2 * i];
  f32x4 b = ((const f32x4*)in)[2 * i + 1];
  union { unsigned short s[8]; u32x4 v; } u;
#pragma unroll
  for (int j = 0; j < 4; j++) { u.s[j] = f2bf(a[j]); u.s[4 + j] = f2bf(b[j]); }
  ((u32x4*)out)[i] = u.v;
}

// ---------- transpose + cast: out[c][r] = bf16(in[r][c]), R,C multiples of 64 ----------
__global__ __launch_bounds__(256) void k_tcast(const float* __restrict__ in,
                                               unsigned short* __restrict__ out, int R, int C) {
  __shared__ unsigned short tile[64][66];
  const int r0 = blockIdx.x * 64, c0 = blockIdx.y * 64;
  const int t = threadIdx.x;
  const int rg = t >> 4, cg = t & 15;
#pragma unroll
  for (int i = 0; i < 4; i++) {
    int rl = rg + i * 16;
    f32x4 v = *(const f32x4*)(in + (size_t)(r0 + rl) * C + c0 + cg * 4);
#pragma unroll
    for (int j = 0; j < 4; j++) tile[rl][cg * 4 + j] = f2bf(v[j]);
  }
  __syncthreads();
#pragma unroll
  for (int i = 0; i < 4; i++) {
    int cl = rg + i * 16;
    u16x4 o;
#pragma unroll
    for (int j = 0; j < 4; j++) o[j] = tile[cg * 4 + j][cl];
    *(u16x4*)(out + (size_t)(c0 + cl) * R + r0 + cg * 4) = o;
  }
}

// ---------- V transpose (bf16): vt[g*128+d][s] = qkv[s][4096 + g*128 + d] ----------
__global__ __launch_bounds__(256) void k_vtrans(const unsigned short* __restrict__ qkv,
                                                unsigned short* __restrict__ vt) {
  __shared__ unsigned short tile[64][66];
  const int r0 = blockIdx.x * 64;  // seq
  const int c0 = blockIdx.y * 64;  // g*128+d in [0,512)
  const int t = threadIdx.x;
  const int rg = t >> 4, cg = t & 15;
#pragma unroll
  for (int i = 0; i < 4; i++) {
    int rl = rg + i * 16;
    u16x4 v = *(const u16x4*)(qkv + (size_t)(r0 + rl) * QKVN + (NQH + NKVH) * HD + c0 + cg * 4);
#pragma unroll
    for (int j = 0; j < 4; j++) tile[rl][cg * 4 + j] = v[j];
  }
  __syncthreads();
#pragma unroll
  for (int i = 0; i < 4; i++) {
    int cl = rg + i * 16;
    u16x4 o;
#pragma unroll
    for (int j = 0; j < 4; j++) o[j] = tile[cg * 4 + j][cl];
    *(u16x4*)(vt + (size_t)(c0 + cl) * SEQ + r0 + cg * 4) = o;
  }
}

// ---------- RoPE in-place on q (heads 0..27) and k (heads 28..31) ----------
__global__ __launch_bounds__(256) void k_rope(unsigned short* __restrict__ qkv,
                                              const float* __restrict__ cosb,
                                              const float* __restrict__ sinb) {
  int idx = blockIdx.x * 256 + threadIdx.x;  // 2048*32*16 total
  int d4 = idx & 15;
  int head = (idx >> 4) & 31;
  int s = idx >> 9;
  unsigned short* row = qkv + (size_t)s * QKVN + head * HD;  // heads 0..31 are contiguous
  int d = d4 * 4;
  u16x4 x1v = *(u16x4*)(row + d);
  u16x4 x2v = *(u16x4*)(row + 64 + d);
  f32x4 c1 = *(const f32x4*)(cosb + s * HD + d);
  f32x4 s1 = *(const f32x4*)(sinb + s * HD + d);
  f32x4 c2 = *(const f32x4*)(cosb + s * HD + 64 + d);
  f32x4 s2 = *(const f32x4*)(sinb + s * HD + 64 + d);
  u16x4 o1, o2;
#pragma unroll
  for (int j = 0; j < 4; j++) {
    float x1 = bf2f(x1v[j]), x2 = bf2f(x2v[j]);
    o1[j] = f2bf(x1 * c1[j] - x2 * s1[j]);
    o2[j] = f2bf(x2 * c2[j] + x1 * s2[j]);
  }
  *(u16x4*)(row + d) = o1;
  *(u16x4*)(row + 64 + d) = o2;
}

// ================= 256 x (NFR*64) 8-wave GEMM =================
// C[M][N] = A[M][K] * Bt[N][K]^T. 8 waves (2M x 4N), per-wave 128 x NFR*16.
// BK=64, LDS dbuf, XOR-swizzle (linear gload dest, inv-swz source).
// NFR=3 -> BN=192 (QKV: grid 8x24=192 blocks), NFR=2 -> BN=128 (O-proj: 8x28=224).
// 4 phases/K-tile (quadrants, N split NB0+NB1); A(t+1) staged ph1, B(t+1) ph2,
// single vmcnt(0) in ph4 placed BEFORE the MFMA region so the wait is covered.
template <int NFR>
__global__ __launch_bounds__(512, 2) void k_gemm256(const unsigned short* __restrict__ A,
                                                    const unsigned short* __restrict__ Bt,
                                                    const float* __restrict__ bias,
                                                    void* __restrict__ Cout,
                                                    int M, int N, int K, int mode) {
  constexpr int BN = NFR * 64;
  constexpr int NB0 = (NFR + 1) / 2;
  __shared__ unsigned short Al[2][256 * 64];
  __shared__ unsigned short Bl[2][BN * 64];

  const int gx = gridDim.x;  // M blocks
  const int nwg = gx * gridDim.y;
  const int lin = blockIdx.y * gx + blockIdx.x;
  const int chunk = nwg >> 3;  // grids are multiples of 8
  const int wg = (lin & 7) * chunk + (lin >> 3);
  const int m0 = (wg % gx) * 256, n0 = (wg / gx) * BN;

  const int t = threadIdx.x;
  const int w = t >> 6, l = t & 63, lg = l >> 4, li = l & 15;
  const int wm = w >> 2, wn = w & 3;  // 2 x 4 waves

  f32x4 acc[8][NFR] = {};
  const int nk = K >> 6;

  bf16x8 af[4][2], bfr[NFR][2];

  const int sRow = (w * 64 + l) >> 3;  // + i*64 per staging step
  const int sSl = (w * 64 + l) & 7;

  auto stA = [&](unsigned short* L, int kt) {
#pragma unroll
    for (int i = 0; i < 4; i++) {
      int row = sRow + i * 64;
      int sl = sSl ^ (row & 7);
      gload16(A + (size_t)(m0 + row) * K + kt * 64 + sl * 8, L + (i * 512 + w * 64) * 8);
    }
  };
  auto stB = [&](unsigned short* L, int kt) {
#pragma unroll
    for (int i = 0; i < NFR; i++) {
      int row = sRow + i * 64;
      int sl = sSl ^ (row & 7);
      gload16(Bt + (size_t)(n0 + row) * K + kt * 64 + sl * 8, L + (i * 512 + w * 64) * 8);
    }
  };
  auto rdA = [&](const unsigned short* buf, int mq) {
#pragma unroll
    for (int mi = 0; mi < 4; mi++) {
      int row = wm * 128 + mq * 64 + mi * 16 + li;
#pragma unroll
      for (int ks = 0; ks < 2; ks++)
        af[mi][ks] = __builtin_bit_cast(
            bf16x8, *(const u32x4*)(buf + row * 64 + ((ks * 32 + lg * 8) ^ ((row & 7) << 3))));
    }
  };
  auto rdB = [&](const unsigned short* buf, int flo, int fhi) {
#pragma unroll
    for (int f = 0; f < NFR; f++)
      if (f >= flo && f < fhi) {
        int row = wn * (NFR * 16) + f * 16 + li;
#pragma unroll
        for (int ks = 0; ks < 2; ks++)
          bfr[f][ks] = __builtin_bit_cast(
              bf16x8, *(const u32x4*)(buf + row * 64 + ((ks * 32 + lg * 8) ^ ((row & 7) << 3))));
      }
  };
  auto mfmaQ = [&](int mq, int flo, int fhi) {
    __builtin_amdgcn_s_setprio(1);
#pragma unroll
    for (int mi = 0; mi < 4; mi++)
#pragma unroll
      for (int f = 0; f < NFR; f++)
        if (f >= flo && f < fhi)
#pragma unroll
          for (int ks = 0; ks < 2; ks++)
            acc[mq * 4 + mi][f] = __builtin_amdgcn_mfma_f32_16x16x32_bf16(
                af[mi][ks], bfr[f][ks], acc[mq * 4 + mi][f], 0, 0, 0);
    __builtin_amdgcn_s_setprio(0);
  };

  // prologue
  stA(Al[0], 0);
  stB(Bl[0], 0);
  asm volatile("s_waitcnt vmcnt(0)" ::: "memory");
  __builtin_amdgcn_s_barrier();

  for (int kt = 0; kt < nk; kt++) {
    const int cur = kt & 1;
    const unsigned short* Ab = Al[cur];
    const unsigned short* Bb = Bl[cur];
    const bool st = kt + 1 < nk;

    // ---- ph1: q(0, B0) ; stage A(t+1) ----
    rdA(Ab, 0);
    rdB(Bb, 0, NB0);
    if (st) stA(Al[cur ^ 1], kt + 1);
    __builtin_amdgcn_s_barrier();
    asm volatile("s_waitcnt lgkmcnt(0)" ::: "memory");
    __builtin_amdgcn_sched_barrier(0);
    mfmaQ(0, 0, NB0);
    __builtin_amdgcn_s_barrier();

    // ---- ph2: q(0, B1) ; stage B(t+1) ----
    rdB(Bb, NB0, NFR);
    if (st) stB(Bl[cur ^ 1], kt + 1);
    __builtin_amdgcn_s_barrier();
    asm volatile("s_waitcnt lgkmcnt(0)" ::: "memory");
    __builtin_amdgcn_sched_barrier(0);
    mfmaQ(0, NB0, NFR);
    __builtin_amdgcn_s_barrier();

    // ---- ph3: q(1, B0) ----
    rdA(Ab, 1);
    rdB(Bb, 0, NB0);
    __builtin_amdgcn_s_barrier();
    asm volatile("s_waitcnt lgkmcnt(0)" ::: "memory");
    __builtin_amdgcn_sched_barrier(0);
    mfmaQ(1, 0, NB0);
    __builtin_amdgcn_s_barrier();

    // ---- ph4: q(1, B1) ; vmcnt(0) covered by the MFMA region ----
    rdB(Bb, NB0, NFR);
    __builtin_amdgcn_s_barrier();
    asm volatile("s_waitcnt lgkmcnt(0) vmcnt(0)" ::: "memory");
    __builtin_amdgcn_sched_barrier(0);
    mfmaQ(1, NB0, NFR);
    __builtin_amdgcn_s_barrier();
  }

  if (mode == 0) {
    float bv[NFR];
#pragma unroll
    for (int nf = 0; nf < NFR; nf++) bv[nf] = bias[n0 + wn * (NFR * 16) + nf * 16 + li];
    unsigned short* C16 = (unsigned short*)Cout;
#pragma unroll
    for (int mf = 0; mf < 8; mf++)
#pragma unroll
      for (int nf = 0; nf < NFR; nf++)
#pragma unroll
        for (int r = 0; r < 4; r++) {
          int m = m0 + wm * 128 + mf * 16 + lg * 4 + r;
          int n = n0 + wn * (NFR * 16) + nf * 16 + li;
          C16[(size_t)m * N + n] = f2bf(acc[mf][nf][r] + bv[nf]);
        }
  } else {
    float* Cf = (float*)Cout;
#pragma unroll
    for (int mf = 0; mf < 8; mf++)
#pragma unroll
      for (int nf = 0; nf < NFR; nf++)
#pragma unroll
        for (int r = 0; r < 4; r++) {
          int m = m0 + wm * 128 + mf * 16 + lg * 4 + r;
          int n = n0 + wn * (NFR * 16) + nf * 16 + li;
          Cf[(size_t)m * N + n] = acc[mf][nf][r];
        }
  }
}

// ---------- flash attention, sliding window, GQA ----------
// block = (qb, h): 64 q rows, head h (kv group h/7). 4 waves x 16 rows.
__global__ __launch_bounds__(256) void k_attn(const unsigned short* __restrict__ qkv,
                                              const unsigned short* __restrict__ vt,
                                              unsigned short* __restrict__ attnout) {
  __shared__ unsigned short Kl[64 * 128];
  __shared__ unsigned short Vl[128 * 64];
  __shared__ unsigned short Pl[4][16 * 64];

  const int qb = blockIdx.x;
  const int h = blockIdx.y;
  const int g = h / 7;
  const int t = threadIdx.x;
  const int w = t >> 6, l = t & 63, lg = l >> 4, li = l & 15;

  bf16x8 qf[4];
  {
    const int qrow = qb * 64 + w * 16 + li;
    const unsigned short* qp = qkv + (size_t)qrow * QKVN + h * HD;
#pragma unroll
    for (int ks = 0; ks < 4; ks++)
      qf[ks] = __builtin_bit_cast(bf16x8, *(const u32x4*)(qp + ks * 32 + lg * 8));
  }

  f32x4 oacc[8] = {};
  float mr[4], lr[4];
#pragma unroll
  for (int r = 0; r < 4; r++) { mr[r] = -1e30f; lr[r] = 0.f; }

  const int kt_lo = qb >= 16 ? qb - 16 : 0;
  const float scale = 0.088388347648318447f;  // 1/sqrt(128)

  for (int kt = kt_lo; kt <= qb; kt++) {
    __syncthreads();
    // stage K tile [64 keys][128 d], swizzled
#pragma unroll
    for (int i = 0; i < 4; i++) {
      int s = t + i * 256;
      int row = s >> 4, sl = s & 15;
      u32x4 v = *(const u32x4*)(qkv + (size_t)(kt * 64 + row) * QKVN + NQH * HD + g * HD + sl * 8);
      *(u32x4*)(Kl + row * 128 + ((sl ^ (row & 7)) * 8)) = v;
    }
    // stage V^T tile [128 d][64 keys], swizzled
#pragma unroll
    for (int i = 0; i < 4; i++) {
      int s = t + i * 256;
      int row = s >> 3, sl = s & 7;  // row = d
      u32x4 v = *(const u32x4*)(vt + (size_t)(g * HD + row) * SEQ + kt * 64 + sl * 8);
      *(u32x4*)(Vl + row * 64 + ((sl ^ (row & 7)) * 8)) = v;
    }
    __syncthreads();

    // S = Q K^T
    f32x4 sc[4] = {};
#pragma unroll
    for (int ks = 0; ks < 4; ks++) {
#pragma unroll
      for (int kb = 0; kb < 4; kb++) {
        int key = kb * 16 + li;
        int pos = (ks * 32 + lg * 8) ^ ((key & 7) << 3);
        bf16x8 kf = __builtin_bit_cast(bf16x8, *(const u32x4*)(Kl + key * 128 + pos));
        sc[kb] = __builtin_amdgcn_mfma_f32_16x16x32_bf16(qf[ks], kf, sc[kb], 0, 0, 0);
      }
    }

    // online softmax (rows partition by 16-lane group; reg r = row lg*4+r)
    float alpha[4];
#pragma unroll
    for (int r = 0; r < 4; r++) {
      int qg = qb * 64 + w * 16 + lg * 4 + r;
      float sv[4];
      float mx = -1e30f;
#pragma unroll
      for (int kb = 0; kb < 4; kb++) {
        int kg = kt * 64 + kb * 16 + li;
        float x = sc[kb][r] * scale;
        bool ok = (kg <= qg) && (qg - kg < WIN);
        sv[kb] = ok ? x : -1e30f;
        mx = fmaxf(mx, sv[kb]);
      }
#pragma unroll
      for (int off = 1; off < 16; off <<= 1) mx = fmaxf(mx, __shfl_xor(mx, off));
      float mn = fmaxf(mr[r], mx);
      alpha[r] = __expf(mr[r] - mn);
      float rs = 0.f;
      int q_l = lg * 4 + r;
#pragma unroll
      for (int kb = 0; kb < 4; kb++) {
        float p = (sv[kb] > -1e29f) ? __expf(sv[kb] - mn) : 0.f;
        rs += p;
        Pl[w][q_l * 64 + (((kb * 16 + li) ^ ((q_l & 7) << 3)))] = f2bf(p);
      }
#pragma unroll
      for (int off = 1; off < 16; off <<= 1) rs += __shfl_xor(rs, off);
      lr[r] = lr[r] * alpha[r] + rs;
      mr[r] = mn;
    }
#pragma unroll
    for (int db = 0; db < 8; db++)
#pragma unroll
      for (int r = 0; r < 4; r++) oacc[db][r] *= alpha[r];
    __syncthreads();  // P visible for A-fragment reads

    // O += P V
#pragma unroll
    for (int ks = 0; ks < 2; ks++) {
      int ppos = (ks * 32 + lg * 8) ^ ((li & 7) << 3);
      bf16x8 pf = __builtin_bit_cast(bf16x8, *(const u32x4*)(&Pl[w][li * 64 + ppos]));
#pragma unroll
      for (int db = 0; db < 8; db++) {
        int d = db * 16 + li;
        int vpos = (ks * 32 + lg * 8) ^ ((d & 7) << 3);
        bf16x8 vf = __builtin_bit_cast(bf16x8, *(const u32x4*)(Vl + d * 64 + vpos));
        oacc[db] = __builtin_amdgcn_mfma_f32_16x16x32_bf16(pf, vf, oacc[db], 0, 0, 0);
      }
    }
  }

#pragma unroll
  for (int r = 0; r < 4; r++) {
    float inv = 1.0f / lr[r];
    int qrow = qb * 64 + w * 16 + lg * 4 + r;
#pragma unroll
    for (int db = 0; db < 8; db++)
      attnout[(size_t)qrow * HID + h * HD + db * 16 + li] = f2bf(oacc[db][r] * inv);
  }
}

extern "C" void kernel_launch(void* const* d_in, const int* in_sizes, int n_in,
                              void* d_out, int out_size, void* d_ws, size_t ws_size,
                              hipStream_t stream) {
  const float* hidden = (const float*)d_in[0];
  const float* cosb = (const float*)d_in[1];
  const float* sinb = (const float*)d_in[2];
  const float* wqkv = (const float*)d_in[3];
  const float* bqkv = (const float*)d_in[4];
  const float* wo = (const float*)d_in[5];

  char* ws = (char*)d_ws;
  const size_t SZ_HBF = (size_t)SEQ * HID * 2;          // 14,680,064
  const size_t SZ_WQKVT = (size_t)QKVN * HID * 2;       // 33,030,144
  const size_t SZ_QKV = (size_t)SEQ * QKVN * 2;         // 18,874,368
  const size_t SZ_VT = (size_t)NKVH * HD * SEQ * 2;     // 2,097,152
  unsigned short* hbf = (unsigned short*)ws;
  unsigned short* wqkvT = (unsigned short*)(ws + SZ_HBF);
  unsigned short* qkv = (unsigned short*)(ws + SZ_HBF + SZ_WQKVT);
  unsigned short* vt = (unsigned short*)(ws + SZ_HBF + SZ_WQKVT + SZ_QKV);
  unsigned short* attn = (unsigned short*)(ws + SZ_HBF + SZ_WQKVT + SZ_QKV + SZ_VT);
  unsigned short* woT = wqkvT;  // reuse after QKV GEMM consumed wqkvT

  k_cast8<<<dim3(SEQ * HID / 8 / 256), 256, 0, stream>>>(hidden, hbf, SEQ * HID / 8);
  k_tcast<<<dim3(HID / 64, QKVN / 64), 256, 0, stream>>>(wqkv, wqkvT, HID, QKVN);
  k_gemm256<3><<<dim3(SEQ / 256, QKVN / 192), 512, 0, stream>>>(hbf, wqkvT, bqkv, qkv, SEQ, QKVN, HID, 0);
  k_rope<<<dim3(SEQ * 32 * 16 / 256), 256, 0, stream>>>(qkv, cosb, sinb);
  k_vtrans<<<dim3(SEQ / 64, (NKVH * HD) / 64), 256, 0, stream>>>(qkv, vt);
  k_tcast<<<dim3(HID / 64, HID / 64), 256, 0, stream>>>(wo, woT, HID, HID);
  k_attn<<<dim3(SEQ / 64, NQH), 256, 0, stream>>>(qkv, vt, attn);
  k_gemm256<2><<<dim3(SEQ / 256, HID / 128), 512, 0, stream>>>(attn, woT, nullptr, d_out, SEQ, HID, HID, 1);
}